// Round 9
// baseline (201.653 us; speedup 1.0000x reference)
//
#include <hip/hip_runtime.h>
#include <hip/hip_bf16.h>
#include <math.h>

#define BB 64
#define PP 10
#define SS 64
#define KK 32
#define HH 128
#define NN 33          // KK+1
#define TOTAL (BB*KK)  // 2048
#define G3 384         // 3*HH

// workspace layout (in floats)
// W_msg repack: wpos[2][128] | wa4[32][128][4] | wj4[32][128][4]
#define WPOS_OFF 0
#define WA4_OFF  256
#define WJ4_OFF  (256 + 16384)
#define WT_SZ    33024
#define U_OFF  WT_SZ
#define UV_SZ  (BB*NN*HH)
#define V_OFF  (U_OFF + UV_SZ)
#define PL_OFF (V_OFF + UV_SZ)
#define PL_SZ  (BB*KK*HH)
#define OS_OFF (PL_OFF + PL_SZ)

// seq_start_end may arrive as int32 (x64 off) or int64 (x64 on).
__device__ inline void get_se(const int* __restrict__ sse, int b, int& start, int& endv) {
    if (sse[1] == 0) { start = sse[4 * b]; endv = sse[4 * b + 2]; }   // int64
    else             { start = sse[2 * b]; endv = sse[2 * b + 1]; }   // int32
}

// ---------------- K0: repack W_msg (128x258) ----------------
__global__ __launch_bounds__(256) void k0_repack(const float* __restrict__ Wmsg,
                                                 float* __restrict__ wt) {
    int idx = blockIdx.x * 256 + threadIdx.x;
    if (idx < 256) {
        int c = idx >> 7, h = idx & 127;
        wt[WPOS_OFF + idx] = Wmsg[h * 258 + c];
    } else if (idx < WT_SZ) {
        int j = idx - 256;
        int reg = j >> 14;            // 0 -> wa4, 1 -> wj4
        int jj = j & 16383;
        int c4 = jj >> 9, rem = jj & 511, h = rem >> 2, i = rem & 3;
        int col = (reg ? 130 : 2) + 4 * c4 + i;
        wt[256 + j] = Wmsg[h * 258 + col];
    }
}

// ---------------- K1: u[b,a,h], v[b,a,h] ----------------
__global__ __launch_bounds__(256) void k1_uv(
    const float* __restrict__ agent_ctx, const float* __restrict__ ngh_pos,
    const float* __restrict__ ngh_ctx, const int* __restrict__ sse,
    const float* __restrict__ bmsg, const float* __restrict__ wt,
    float* __restrict__ ws)
{
    int b = blockIdx.x / 3, tile = blockIdx.x % 3;
    int a0 = tile * 11;               // 33 = 3 * 11
    int t = threadIdx.x;
    int h = t & 127, half = t >> 7;
    int start, endv;
    get_se(sse, b, start, endv);

    const float* rp[11];
    float px[11], py[11];
    #pragma unroll
    for (int i = 0; i < 11; i++) {
        int a = a0 + i;
        if (a == 0) { rp[i] = agent_ctx + b * HH; px[i] = 0.f; py[i] = 0.f; }
        else {
            int ic = min(max(start + a - 1, 0), TOTAL - 1);
            rp[i] = ngh_ctx + ic * HH;
            px[i] = ngh_pos[ic * 2]; py[i] = ngh_pos[ic * 2 + 1];
        }
    }
    const float4* w4base = (const float4*)(wt + (half ? WJ4_OFF : WA4_OFF));
    float acc[11];
    #pragma unroll
    for (int i = 0; i < 11; i++) acc[i] = 0.f;

    for (int c4 = 0; c4 < 32; c4++) {
        float4 w4 = w4base[c4 * 128 + h];
        #pragma unroll
        for (int i = 0; i < 11; i++) {
            float4 cv = ((const float4*)rp[i])[c4];
            acc[i] += w4.x * cv.x + w4.y * cv.y + w4.z * cv.z + w4.w * cv.w;
        }
    }
    float wp0 = wt[WPOS_OFF + h], wp1 = wt[WPOS_OFF + 128 + h];
    float bm = bmsg[h];
    float* uout = ws + U_OFF;
    float* vout = ws + V_OFF;
    #pragma unroll
    for (int i = 0; i < 11; i++) {
        int a = a0 + i;
        float pt = px[i] * wp0 + py[i] * wp1;
        if (half == 0) uout[(b * NN + a) * HH + h] = acc[i] - pt;
        else           vout[(b * NN + a) * HH + h] = acc[i] + pt + bm;
    }
}

// ---------------- K2: pooled[b,a-1,h] = sum_{j != a} relu(u[a]+v[j]) ----------------
__global__ __launch_bounds__(128) void k2_pooled(const float* __restrict__ ws_u,
                                                 const float* __restrict__ ws_v,
                                                 float* __restrict__ pooled)
{
    int b = blockIdx.x >> 5, am1 = blockIdx.x & 31;
    int a = am1 + 1;
    int h = threadIdx.x;
    float uval = ws_u[(b * NN + a) * HH + h];
    const float* vb = ws_v + b * NN * HH + h;
    float s = 0.f;
    #pragma unroll 11
    for (int j = 0; j < NN; j++) s += fmaxf(uval + vb[j * HH], 0.f);
    s -= fmaxf(uval + vb[a * HH], 0.f);
    pooled[(b * KK + am1) * HH + h] = s;
}

// ---------------- K3: gi/gh matmuls + GRU + per-b output sum ----------------
// 384 thr: 192 gi-lanes + 192 gh-lanes; each owns (row 0..47, quarter 0..3)
// -> only 8 float4 (32 VGPR) of persistent weights per thread (compiler-safe;
//    the 128-VGPR variant was demoted to scratch in R4/R5, VGPR_Count 84-88).
// Quarter partials combine via 2x shfl_xor (lanes 4k..4k+3 = same row).
// Phase 1: barrier-free dots for all 32 nodes -> LDS. Phase 2: parallel GRU.
__global__ __launch_bounds__(384, 2) void k3_gru(
    const float* __restrict__ pooled, const float* __restrict__ ngh_ctx,
    const int* __restrict__ sse,
    const float* __restrict__ Wih, const float* __restrict__ Whh,
    const float* __restrict__ bih, const float* __restrict__ bhh,
    float* __restrict__ outsum)
{
    int b = blockIdx.x >> 3, hc = blockIdx.x & 7;
    int t = threadIdx.x;
    __shared__ float gi_s[KK][48];
    __shared__ float gh_s[KK][48];
    __shared__ float hn_s[KK * 16];
    int start, endv;
    get_se(sse, b, start, endv);

    bool is_gh = (t >= 192);
    int r4 = is_gh ? (t - 192) : t;     // 0..191
    int row = r4 >> 2;                  // 0..47
    int q   = r4 & 3;                   // quarter of the 128-d dot
    int grow = (row >> 4) * HH + hc * 16 + (row & 15);

    const float4* Wr = (const float4*)((is_gh ? Whh : Wih) + grow * HH + q * 32);
    float4 w[8];
    #pragma unroll
    for (int i = 0; i < 8; i++) w[i] = Wr[i];
    float bias = is_gh ? bhh[grow] : bih[grow];

    for (int n = 0; n < KK; n++) {
        int ic = min(max(start + n, 0), TOTAL - 1);
        const float4* vp = (const float4*)((is_gh ? (ngh_ctx + ic * HH)
                                                  : (pooled + (b * KK + n) * HH)) + q * 32);
        float d = 0.f;
        #pragma unroll
        for (int i = 0; i < 8; i++) {
            float4 v = vp[i];
            d += w[i].x * v.x + w[i].y * v.y + w[i].z * v.z + w[i].w * v.w;
        }
        d += __shfl_xor(d, 1);          // combine quarters (same wave: 192%4==0)
        d += __shfl_xor(d, 2);
        if (q == 0) {
            if (is_gh) gh_s[n][row] = d + bias;
            else       gi_s[n][row] = d + bias;
        }
    }
    __syncthreads();
    for (int it = t; it < KK * 16; it += 384) {   // 512 GRU items, parallel
        int n = it >> 4, h = it & 15;
        int ic = min(max(start + n, 0), TOTAL - 1);
        float ir = gi_s[n][h], iz = gi_s[n][16 + h], inn = gi_s[n][32 + h];
        float hr = gh_s[n][h], hz = gh_s[n][16 + h], hnn = gh_s[n][32 + h];
        float cval = ngh_ctx[ic * HH + hc * 16 + h];
        float r = 1.f / (1.f + expf(-(ir + hr)));
        float z = 1.f / (1.f + expf(-(iz + hz)));
        float nn = tanhf(inn + r * hnn);
        hn_s[it] = (1.f - z) * nn + z * cval;
    }
    __syncthreads();
    if (t < 16) {
        float s = 0.f;
        #pragma unroll
        for (int n = 0; n < KK; n++) s += hn_s[n * 16 + t];
        outsum[b * HH + hc * 16 + t] = s;
    }
}

// ---------------- K4: validity, output assembly, lane_recon, slow path ----------------
__global__ __launch_bounds__(128) void k4_out(
    const float* __restrict__ lanes_in, const float* __restrict__ ngh_pos,
    const float* __restrict__ lane_ctx, const int* __restrict__ sse,
    const unsigned char* __restrict__ vn8, const int* __restrict__ vn32,
    const float* __restrict__ ws_u, const float* __restrict__ ws_v,
    const float* __restrict__ pooled, const float* __restrict__ outsum,
    const float* __restrict__ ngh_ctx,
    const float* __restrict__ Wih, const float* __restrict__ Whh,
    const float* __restrict__ bih, const float* __restrict__ bhh,
    float* __restrict__ out)
{
    int bp = blockIdx.x;
    int b = bp / PP;
    int t = threadIdx.x;
    __shared__ float lane_s[SS][2];
    __shared__ float mins[4][KK];
    __shared__ int vf_s[KK];
    __shared__ int nan_s, ninv_s;
    __shared__ float pool_s[HH], ctx_s[HH], gi_s[G3], gh_s[G3];

    if (t == 0) nan_s = 0;
    __syncthreads();
    {
        int s = t >> 1, c = t & 1;
        float v = lanes_in[(s * (BB * PP) + bp) * 2 + c];
        lane_s[s][c] = v;
        if (isnan(v)) atomicOr(&nan_s, 1);
    }
    __syncthreads();
    bool lnan = nan_s != 0;
    int start, endv;
    get_se(sse, b, start, endv);
    bool vnb = (vn8[b] != 0) || (vn32[b] != 0);
    {
        int k = t & 31, sh = t >> 5;
        int ic = min(max(start + k, 0), TOTAL - 1);
        float nx = ngh_pos[ic * 2], ny = ngh_pos[ic * 2 + 1];
        float m;
        if (lnan) m = nx * nx + ny * ny;
        else {
            m = 3.4e38f;
            for (int s = sh * 16; s < sh * 16 + 16; s++) {
                float dx = nx - lane_s[s][0], dy = ny - lane_s[s][1];
                m = fminf(m, dx * dx + dy * dy);
            }
        }
        mins[sh][k] = m;
    }
    __syncthreads();
    if (t < KK) {
        float m = fminf(fminf(mins[0][t], mins[1][t]), fminf(mins[2][t], mins[3][t]));
        bool mask = (start + t) < endv;
        bool valid = (m < 25.0f) && mask && vnb;
        vf_s[t] = valid ? 1 : 0;
    }
    __syncthreads();
    if (t == 0) {
        int c = 0;
        for (int k2 = 0; k2 < KK; k2++) c += 1 - vf_s[k2];
        ninv_s = c;
    }
    out[bp * HH + t] = lane_ctx[bp * HH + t];
    __syncthreads();

    float* out2 = out + BB * PP * HH;
    if (ninv_s == 0) {
        out2[bp * HH + t] = outsum[b * HH + t];
        return;
    }
    float acc = 0.f;
    const float* ub = ws_u + b * NN * HH;
    const float* vb = ws_v + b * NN * HH;
    for (int am1 = 0; am1 < KK; am1++) {
        if (!vf_s[am1]) continue;
        int a = am1 + 1;
        {
            float pc = pooled[(b * KK + am1) * HH + t];
            float uval = ub[a * HH + t];
            for (int j = 1; j < NN; j++)
                if (!vf_s[j - 1]) pc -= fmaxf(uval + vb[j * HH + t], 0.f);
            pool_s[t] = pc;
            int ic = min(max(start + am1, 0), TOTAL - 1);
            ctx_s[t] = ngh_ctx[ic * HH + t];
        }
        __syncthreads();
        for (int r = t; r < G3; r += HH) {
            const float* wr  = Wih + r * HH;
            const float* wr2 = Whh + r * HH;
            float a0 = 0.f, a1 = 0.f;
            for (int d = 0; d < HH; d++) { a0 += wr[d] * pool_s[d]; a1 += wr2[d] * ctx_s[d]; }
            gi_s[r] = a0 + bih[r];
            gh_s[r] = a1 + bhh[r];
        }
        __syncthreads();
        {
            float r = 1.f / (1.f + expf(-(gi_s[t] + gh_s[t])));
            float z = 1.f / (1.f + expf(-(gi_s[HH + t] + gh_s[HH + t])));
            float n = tanhf(gi_s[2 * HH + t] + r * gh_s[2 * HH + t]);
            acc += (1.f - z) * n + z * ctx_s[t];
        }
        __syncthreads();
    }
    out2[bp * HH + t] = acc;
}

extern "C" void kernel_launch(void* const* d_in, const int* in_sizes, int n_in,
                              void* d_out, int out_size, void* d_ws, size_t ws_size,
                              hipStream_t stream)
{
    const float* agent_ctx = (const float*)d_in[1];
    const float* ngh_pos   = (const float*)d_in[2];
    const float* ngh_ctx   = (const float*)d_in[3];
    const float* lanes     = (const float*)d_in[4];
    const float* lane_ctx  = (const float*)d_in[5];
    const int*   sse       = (const int*)d_in[7];
    const unsigned char* vn8 = (const unsigned char*)d_in[8];
    const int*   vn32      = (const int*)d_in[8];
    const float* Wmsg = (const float*)d_in[9];
    const float* bmsg = (const float*)d_in[10];
    const float* Wih  = (const float*)d_in[11];
    const float* Whh  = (const float*)d_in[12];
    const float* bih  = (const float*)d_in[13];
    const float* bhh  = (const float*)d_in[14];
    float* ws  = (float*)d_ws;
    float* out = (float*)d_out;

    k0_repack<<<dim3(129), dim3(256), 0, stream>>>(Wmsg, ws);
    k1_uv<<<dim3(192), dim3(256), 0, stream>>>(agent_ctx, ngh_pos, ngh_ctx, sse,
                                               bmsg, ws, ws);
    k2_pooled<<<dim3(2048), dim3(128), 0, stream>>>(ws + U_OFF, ws + V_OFF, ws + PL_OFF);
    k3_gru<<<dim3(512), dim3(384), 0, stream>>>(ws + PL_OFF, ngh_ctx, sse,
                                                Wih, Whh, bih, bhh, ws + OS_OFF);
    k4_out<<<dim3(640), dim3(128), 0, stream>>>(lanes, ngh_pos, lane_ctx, sse, vn8, vn32,
                                                ws + U_OFF, ws + V_OFF, ws + PL_OFF,
                                                ws + OS_OFF, ngh_ctx,
                                                Wih, Whh, bih, bhh, out);
}

// Round 13
// 117.472 us; speedup vs baseline: 1.7166x; 1.7166x over previous
//
#include <hip/hip_runtime.h>
#include <hip/hip_bf16.h>
#include <math.h>

#define BB 64
#define PP 10
#define SS 64
#define KK 32
#define HH 128
#define NN 33          // KK+1
#define TOTAL (BB*KK)  // 2048
#define G3 384         // 3*HH

// workspace layout (in floats)
// W_msg repack: wpos[2][128] | wa4[32][128][4] | wj4[32][128][4]
#define WPOS_OFF 0
#define WA4_OFF  256
#define WJ4_OFF  (256 + 16384)
#define WT_SZ    33024
#define U_OFF  WT_SZ
#define UV_SZ  (BB*NN*HH)
#define V_OFF  (U_OFF + UV_SZ)
#define PL_OFF (V_OFF + UV_SZ)
#define PL_SZ  (BB*KK*HH)
#define OS_OFF (PL_OFF + PL_SZ)

// seq_start_end may arrive as int32 (x64 off) or int64 (x64 on).
__device__ inline void get_se(const int* __restrict__ sse, int b, int& start, int& endv) {
    if (sse[1] == 0) { start = sse[4 * b]; endv = sse[4 * b + 2]; }   // int64
    else             { start = sse[2 * b]; endv = sse[2 * b + 1]; }   // int32
}

// ---------------- K0: repack W_msg (128x258) ----------------
__global__ __launch_bounds__(256) void k0_repack(const float* __restrict__ Wmsg,
                                                 float* __restrict__ wt) {
    int idx = blockIdx.x * 256 + threadIdx.x;
    if (idx < 256) {
        int c = idx >> 7, h = idx & 127;
        wt[WPOS_OFF + idx] = Wmsg[h * 258 + c];
    } else if (idx < WT_SZ) {
        int j = idx - 256;
        int reg = j >> 14;            // 0 -> wa4, 1 -> wj4
        int jj = j & 16383;
        int c4 = jj >> 9, rem = jj & 511, h = rem >> 2, i = rem & 3;
        int col = (reg ? 130 : 2) + 4 * c4 + i;
        wt[256 + j] = Wmsg[h * 258 + col];
    }
}

// ---------------- K1: u[b,a,h], v[b,a,h] ----------------
// R12: k1 had k3's disease (wave-uniform GLOBAL loads in the dot loop, and
// only 192 blocks on 256 CUs). Same medicine as k3: LDS-stage the ctx rows,
// raise block count 192 -> 704 (11 tiles x 3 a's per b) for latency hiding.
__global__ __launch_bounds__(256) void k1_uv(
    const float* __restrict__ agent_ctx, const float* __restrict__ ngh_pos,
    const float* __restrict__ ngh_ctx, const int* __restrict__ sse,
    const float* __restrict__ bmsg, const float* __restrict__ wt,
    float* __restrict__ ws)
{
    int b = blockIdx.x / 11, tile = blockIdx.x % 11;
    int a0 = tile * 3;                // 33 = 11 * 3
    int t = threadIdx.x;
    int h = t & 127, half = t >> 7;   // waves 0,1 -> u ; waves 2,3 -> v
    int start, endv;
    get_se(sse, b, start, endv);

    __shared__ __align__(16) float ctx_s[3][HH];   // 1.5 KB
    __shared__ float pxy_s[3][2];

    if (t < 96) {                     // stage 3 ctx rows, coalesced float4
        int i = t >> 5, c = t & 31;
        int a = a0 + i;
        const float* src;
        if (a == 0) src = agent_ctx + (size_t)b * HH;
        else {
            int ic = min(max(start + a - 1, 0), TOTAL - 1);
            src = ngh_ctx + (size_t)ic * HH;
        }
        ((float4*)&ctx_s[i][0])[c] = ((const float4*)src)[c];
    }
    if (t < 3) {
        int a = a0 + t;
        float px = 0.f, py = 0.f;
        if (a > 0) {
            int ic = min(max(start + a - 1, 0), TOTAL - 1);
            px = ngh_pos[ic * 2]; py = ngh_pos[ic * 2 + 1];
        }
        pxy_s[t][0] = px; pxy_s[t][1] = py;
    }
    __syncthreads();

    const float4* w4base = (const float4*)(wt + (half ? WJ4_OFF : WA4_OFF));
    float acc[3] = {0.f, 0.f, 0.f};
    for (int c4 = 0; c4 < 32; c4++) {
        float4 w4 = w4base[c4 * 128 + h];              // coalesced 16B/lane (L2)
        #pragma unroll
        for (int i = 0; i < 3; i++) {
            float4 cv = ((const float4*)&ctx_s[i][0])[c4];  // LDS broadcast, free
            acc[i] += w4.x * cv.x + w4.y * cv.y + w4.z * cv.z + w4.w * cv.w;
        }
    }
    float wp0 = wt[WPOS_OFF + h], wp1 = wt[WPOS_OFF + 128 + h];
    float bm = bmsg[h];
    float* uout = ws + U_OFF;
    float* vout = ws + V_OFF;
    #pragma unroll
    for (int i = 0; i < 3; i++) {
        int a = a0 + i;
        float pt = pxy_s[i][0] * wp0 + pxy_s[i][1] * wp1;
        if (half == 0) uout[(b * NN + a) * HH + h] = acc[i] - pt;
        else           vout[(b * NN + a) * HH + h] = acc[i] + pt + bm;
    }
}

// ---------------- K2: pooled[b,a-1,h] = sum_{j != a} relu(u[a]+v[j]) ----------------
__global__ __launch_bounds__(128) void k2_pooled(const float* __restrict__ ws_u,
                                                 const float* __restrict__ ws_v,
                                                 float* __restrict__ pooled)
{
    int b = blockIdx.x >> 5, am1 = blockIdx.x & 31;
    int a = am1 + 1;
    int h = threadIdx.x;
    float uval = ws_u[(b * NN + a) * HH + h];
    const float* vb = ws_v + b * NN * HH + h;
    float s = 0.f;
    #pragma unroll 11
    for (int j = 0; j < NN; j++) s += fmaxf(uval + vb[j * HH], 0.f);
    s -= fmaxf(uval + vb[a * HH], 0.f);
    pooled[(b * KK + am1) * HH + h] = s;
}

// ---------------- K3: gi/gh matmuls + GRU + per-b output sum ----------------
// R9 evidence: VGPR=32 (no spill) but 91.8 us, VALUBusy 8.9% -> latency-bound
// on per-node GLOBAL vector loads. Fix: stage pooled+ctx in LDS once per
// block (guide G3); node loop reads LDS with per-q rotated chunk order
// (idx=(s+2q)&7) so the 4 q-groups hit disjoint bank sets (conflict-free).
__global__ __launch_bounds__(384) void k3_gru(
    const float* __restrict__ pooled, const float* __restrict__ ngh_ctx,
    const int* __restrict__ sse,
    const float* __restrict__ Wih, const float* __restrict__ Whh,
    const float* __restrict__ bih, const float* __restrict__ bhh,
    float* __restrict__ outsum)
{
    int b = blockIdx.x >> 3, hc = blockIdx.x & 7;
    int t = threadIdx.x;
    __shared__ __align__(16) float pool_s[KK][HH];   // 16 KB
    __shared__ __align__(16) float ctx_s[KK][HH];    // 16 KB
    __shared__ float gi_s[KK][48];                   // 6 KB
    __shared__ float gh_s[KK][48];                   // 6 KB
    __shared__ float hn_s[KK * 16];                  // 2 KB
    int start, endv;
    get_se(sse, b, start, endv);

    // ---- stage pooled & ctx into LDS (coalesced float4) ----
    {
        const float4* ps = (const float4*)(pooled + (size_t)b * KK * HH);
        float4* pd = (float4*)&pool_s[0][0];
        for (int i = t; i < KK * 32; i += 384) pd[i] = ps[i];
        float4* cd = (float4*)&ctx_s[0][0];
        for (int i = t; i < KK * 32; i += 384) {
            int n = i >> 5, c = i & 31;
            int ic = min(max(start + n, 0), TOTAL - 1);
            cd[i] = ((const float4*)(ngh_ctx + (size_t)ic * HH))[c];
        }
    }
    __syncthreads();

    bool is_gh = (t >= 192);
    int r4 = is_gh ? (t - 192) : t;     // 0..191
    int row = r4 >> 2;                  // 0..47
    int q   = r4 & 3;                   // quarter of the 128-d dot
    int grow = (row >> 4) * HH + hc * 16 + (row & 15);

    // weights in rotated chunk order matching the LDS read rotation
    const float4* Wr = (const float4*)((is_gh ? Whh : Wih) + (size_t)grow * HH);
    float4 w[8];
    int cidx[8];
    #pragma unroll
    for (int s = 0; s < 8; s++) {
        int idx = (s + 2 * q) & 7;      // bank set (idx*4)%32: distinct per q
        cidx[s] = q * 8 + idx;
        w[s] = Wr[cidx[s]];
    }
    float bias = is_gh ? bhh[grow] : bih[grow];

    const float4* vecbase = (const float4*)(is_gh ? &ctx_s[0][0] : &pool_s[0][0]);
    for (int n = 0; n < KK; n++) {
        const float4* vp = vecbase + n * 32;
        float d = 0.f;
        #pragma unroll
        for (int s = 0; s < 8; s++) {
            float4 v = vp[cidx[s]];
            d += w[s].x * v.x + w[s].y * v.y + w[s].z * v.z + w[s].w * v.w;
        }
        d += __shfl_xor(d, 1);          // combine quarters (lane-quads)
        d += __shfl_xor(d, 2);
        if (q == 0) {
            if (is_gh) gh_s[n][row] = d + bias;
            else       gi_s[n][row] = d + bias;
        }
    }
    __syncthreads();
    for (int it = t; it < KK * 16; it += 384) {   // 512 GRU items, parallel
        int n = it >> 4, h = it & 15;
        float ir = gi_s[n][h], iz = gi_s[n][16 + h], inn = gi_s[n][32 + h];
        float hr = gh_s[n][h], hz = gh_s[n][16 + h], hnn = gh_s[n][32 + h];
        float cval = ctx_s[n][hc * 16 + h];
        float r = 1.f / (1.f + expf(-(ir + hr)));
        float z = 1.f / (1.f + expf(-(iz + hz)));
        float nn = tanhf(inn + r * hnn);
        hn_s[it] = (1.f - z) * nn + z * cval;
    }
    __syncthreads();
    if (t < 16) {
        float s = 0.f;
        #pragma unroll
        for (int n = 0; n < KK; n++) s += hn_s[n * 16 + t];
        outsum[b * HH + hc * 16 + t] = s;
    }
}

// ---------------- K4: validity, output assembly, lane_recon, slow path ----------------
__global__ __launch_bounds__(128) void k4_out(
    const float* __restrict__ lanes_in, const float* __restrict__ ngh_pos,
    const float* __restrict__ lane_ctx, const int* __restrict__ sse,
    const unsigned char* __restrict__ vn8, const int* __restrict__ vn32,
    const float* __restrict__ ws_u, const float* __restrict__ ws_v,
    const float* __restrict__ pooled, const float* __restrict__ outsum,
    const float* __restrict__ ngh_ctx,
    const float* __restrict__ Wih, const float* __restrict__ Whh,
    const float* __restrict__ bih, const float* __restrict__ bhh,
    float* __restrict__ out)
{
    int bp = blockIdx.x;
    int b = bp / PP;
    int t = threadIdx.x;
    __shared__ float lane_s[SS][2];
    __shared__ float mins[4][KK];
    __shared__ int vf_s[KK];
    __shared__ int nan_s, ninv_s;
    __shared__ float pool_s[HH], ctx_s[HH], gi_s[G3], gh_s[G3];

    if (t == 0) nan_s = 0;
    __syncthreads();
    {
        int s = t >> 1, c = t & 1;
        float v = lanes_in[(s * (BB * PP) + bp) * 2 + c];
        lane_s[s][c] = v;
        if (isnan(v)) atomicOr(&nan_s, 1);
    }
    __syncthreads();
    bool lnan = nan_s != 0;
    int start, endv;
    get_se(sse, b, start, endv);
    bool vnb = (vn8[b] != 0) || (vn32[b] != 0);
    {
        int k = t & 31, sh = t >> 5;
        int ic = min(max(start + k, 0), TOTAL - 1);
        float nx = ngh_pos[ic * 2], ny = ngh_pos[ic * 2 + 1];
        float m;
        if (lnan) m = nx * nx + ny * ny;
        else {
            m = 3.4e38f;
            for (int s = sh * 16; s < sh * 16 + 16; s++) {
                float dx = nx - lane_s[s][0], dy = ny - lane_s[s][1];
                m = fminf(m, dx * dx + dy * dy);
            }
        }
        mins[sh][k] = m;
    }
    __syncthreads();
    if (t < KK) {
        float m = fminf(fminf(mins[0][t], mins[1][t]), fminf(mins[2][t], mins[3][t]));
        bool mask = (start + t) < endv;
        bool valid = (m < 25.0f) && mask && vnb;
        vf_s[t] = valid ? 1 : 0;
    }
    __syncthreads();
    if (t == 0) {
        int c = 0;
        for (int k2 = 0; k2 < KK; k2++) c += 1 - vf_s[k2];
        ninv_s = c;
    }
    out[bp * HH + t] = lane_ctx[bp * HH + t];
    __syncthreads();

    float* out2 = out + BB * PP * HH;
    if (ninv_s == 0) {
        out2[bp * HH + t] = outsum[b * HH + t];
        return;
    }
    float acc = 0.f;
    const float* ub = ws_u + b * NN * HH;
    const float* vb = ws_v + b * NN * HH;
    for (int am1 = 0; am1 < KK; am1++) {
        if (!vf_s[am1]) continue;
        int a = am1 + 1;
        {
            float pc = pooled[(b * KK + am1) * HH + t];
            float uval = ub[a * HH + t];
            for (int j = 1; j < NN; j++)
                if (!vf_s[j - 1]) pc -= fmaxf(uval + vb[j * HH + t], 0.f);
            pool_s[t] = pc;
            int ic = min(max(start + am1, 0), TOTAL - 1);
            ctx_s[t] = ngh_ctx[ic * HH + t];
        }
        __syncthreads();
        for (int r = t; r < G3; r += HH) {
            const float* wr  = Wih + r * HH;
            const float* wr2 = Whh + r * HH;
            float a0 = 0.f, a1 = 0.f;
            for (int d = 0; d < HH; d++) { a0 += wr[d] * pool_s[d]; a1 += wr2[d] * ctx_s[d]; }
            gi_s[r] = a0 + bih[r];
            gh_s[r] = a1 + bhh[r];
        }
        __syncthreads();
        {
            float r = 1.f / (1.f + expf(-(gi_s[t] + gh_s[t])));
            float z = 1.f / (1.f + expf(-(gi_s[HH + t] + gh_s[HH + t])));
            float n = tanhf(gi_s[2 * HH + t] + r * gh_s[2 * HH + t]);
            acc += (1.f - z) * n + z * ctx_s[t];
        }
        __syncthreads();
    }
    out2[bp * HH + t] = acc;
}

extern "C" void kernel_launch(void* const* d_in, const int* in_sizes, int n_in,
                              void* d_out, int out_size, void* d_ws, size_t ws_size,
                              hipStream_t stream)
{
    const float* agent_ctx = (const float*)d_in[1];
    const float* ngh_pos   = (const float*)d_in[2];
    const float* ngh_ctx   = (const float*)d_in[3];
    const float* lanes     = (const float*)d_in[4];
    const float* lane_ctx  = (const float*)d_in[5];
    const int*   sse       = (const int*)d_in[7];
    const unsigned char* vn8 = (const unsigned char*)d_in[8];
    const int*   vn32      = (const int*)d_in[8];
    const float* Wmsg = (const float*)d_in[9];
    const float* bmsg = (const float*)d_in[10];
    const float* Wih  = (const float*)d_in[11];
    const float* Whh  = (const float*)d_in[12];
    const float* bih  = (const float*)d_in[13];
    const float* bhh  = (const float*)d_in[14];
    float* ws  = (float*)d_ws;
    float* out = (float*)d_out;

    k0_repack<<<dim3(129), dim3(256), 0, stream>>>(Wmsg, ws);
    k1_uv<<<dim3(704), dim3(256), 0, stream>>>(agent_ctx, ngh_pos, ngh_ctx, sse,
                                               bmsg, ws, ws);
    k2_pooled<<<dim3(2048), dim3(128), 0, stream>>>(ws + U_OFF, ws + V_OFF, ws + PL_OFF);
    k3_gru<<<dim3(512), dim3(384), 0, stream>>>(ws + PL_OFF, ngh_ctx, sse,
                                                Wih, Whh, bih, bhh, ws + OS_OFF);
    k4_out<<<dim3(640), dim3(128), 0, stream>>>(lanes, ngh_pos, lane_ctx, sse, vn8, vn32,
                                                ws + U_OFF, ws + V_OFF, ws + PL_OFF,
                                                ws + OS_OFF, ngh_ctx,
                                                Wih, Whh, bih, bhh, out);
}